// Round 8
// baseline (366.544 us; speedup 1.0000x reference)
//
#include <hip/hip_runtime.h>
#include <cfloat>
#include <cstdint>

// Model2c round 8: concat-convs fully split by channel segment so every GEMM
// A-operand is a plain streaming row read (no indirection anywhere in a GEMM):
//   conv7: Z2 = att2*W7top (M=T*n3!), Zb7 = att1*W7bot
//          cv7[n] = relu(b7 + sum_k Z2[up4[nb_k]] + Zb7[nb_k])
//   conv8: Z7s = cv7*W8top, Zb8 = att0*W8bot
//          cv8[n] = relu(b8 + sum_k Z7s[up5[nb_k]] + Zb8[nb_k])
// GEMM FLOPs halved vs r7; C written back via LDS staging as full 128B lines
// (r7 showed 3x write amplification from scalar ushort stores).
// conv1/conv2 keep the r6 reg-direct path. ws ~191 MB.

constexpr int T  = 16;
constexpr int n5 = 10242, n4 = 2562, n3 = 642;
constexpr int K  = 7;

using bf16x8 = __attribute__((ext_vector_type(8))) short;
using f32x4  = __attribute__((ext_vector_type(4))) float;

static __device__ __forceinline__ float bf2f(unsigned short u) {
    return __uint_as_float((unsigned)u << 16);
}
static __device__ __forceinline__ unsigned short f2bf(float x) {
    unsigned u = __float_as_uint(x);
    u += 0x7FFF + ((u >> 16) & 1);
    return (unsigned short)(u >> 16);
}

// ---------------------------------------------------------------------------
// conv0: c0f/c0a (bf16) + fused cos -> att0 = bf16[c0f*m | c0a*m]
// ---------------------------------------------------------------------------
__global__ __launch_bounds__(256) void conv0_kernel(
    const float* __restrict__ frame, const float* __restrict__ aem,
    const float* __restrict__ W0f, const float* __restrict__ b0f,
    const float* __restrict__ W0a, const float* __restrict__ b0a,
    const int* __restrict__ neigh5,
    unsigned short* __restrict__ c0f, unsigned short* __restrict__ c0a,
    unsigned short* __restrict__ att0)
{
    const int g = threadIdx.x >> 5;
    const int d = threadIdx.x & 31;
    const int per_t = (n5 + 7) / 8;
    const int t = blockIdx.x / per_t;
    const int n = (blockIdx.x % per_t) * 8 + g;
    if (n >= n5) return;

    float accf = b0f[d];
    float acca = b0a[d];
    const int* nb = neigh5 + n * K;
    #pragma unroll
    for (int k = 0; k < K; ++k) {
        const int j = nb[k];
        const float* fr = frame + ((size_t)t * n5 + j) * 3;
        const float av = aem[(size_t)t * n5 + j];
        accf = fmaf(fr[0], W0f[(k * 3 + 0) * 32 + d], accf);
        accf = fmaf(fr[1], W0f[(k * 3 + 1) * 32 + d], accf);
        accf = fmaf(fr[2], W0f[(k * 3 + 2) * 32 + d], accf);
        acca = fmaf(av, W0a[k * 32 + d], acca);
    }
    accf = fmaxf(accf, 0.f);
    acca = fmaxf(acca, 0.f);

    float dot = accf * acca, ff = accf * accf, aa = acca * acca;
    #pragma unroll
    for (int m = 1; m < 32; m <<= 1) {
        dot += __shfl_xor(dot, m, 32);
        ff  += __shfl_xor(ff,  m, 32);
        aa  += __shfl_xor(aa,  m, 32);
    }
    const float mm = dot / fmaxf(sqrtf(ff) * sqrtf(aa), 1e-8f);
    const size_t base = ((size_t)t * n5 + n) * 32;
    c0f[base + d] = f2bf(accf);
    c0a[base + d] = f2bf(acca);
    const size_t abase = ((size_t)t * n5 + n) * 64;
    att0[abase + d]      = f2bf(accf * mm);
    att0[abase + 32 + d] = f2bf(acca * mm);
}

// ---------------------------------------------------------------------------
// pool (bf16 -> bf16)
// ---------------------------------------------------------------------------
template<int C>
__global__ __launch_bounds__(256) void pool_kernel(
    const unsigned short* __restrict__ in, const int* __restrict__ pidx,
    int Nin, int Nout, unsigned short* __restrict__ out)
{
    constexpr int C8 = C / 8;
    const int idx = blockIdx.x * 256 + threadIdx.x;
    if (idx >= T * Nout * C8) return;
    const int c8 = idx % C8;
    const int n  = (idx / C8) % Nout;
    const int t  = idx / (C8 * Nout);
    const int* pp = pidx + n * K;
    float m[8];
    #pragma unroll
    for (int j = 0; j < 8; ++j) m[j] = -FLT_MAX;
    #pragma unroll
    for (int k = 0; k < K; ++k) {
        const uint4 v = reinterpret_cast<const uint4*>(in)[((size_t)t * Nin + pp[k]) * C8 + c8];
        const unsigned short* s = reinterpret_cast<const unsigned short*>(&v);
        #pragma unroll
        for (int j = 0; j < 8; ++j) m[j] = fmaxf(m[j], bf2f(s[j]));
    }
    unsigned short o[8];
    #pragma unroll
    for (int j = 0; j < 8; ++j) o[j] = f2bf(m[j]);
    reinterpret_cast<uint4*>(out)[((size_t)t * Nout + n) * C8 + c8] =
        *reinterpret_cast<const uint4*>(o);
}

// ---------------------------------------------------------------------------
// cosatt: m = cos(f,a); att = bf16[f*m | a*m]
// ---------------------------------------------------------------------------
template<int C, int NN>
__global__ __launch_bounds__(256) void cosatt_kernel(
    const unsigned short* __restrict__ f, const unsigned short* __restrict__ a,
    unsigned short* __restrict__ att)
{
    constexpr int CPL = C / 64;
    const int w = threadIdx.x >> 6, lane = threadIdx.x & 63;
    const int idx = blockIdx.x * 4 + w;
    if (idx >= T * NN) return;
    const unsigned short* fr = f + (size_t)idx * C;
    const unsigned short* ar = a + (size_t)idx * C;
    float xs[CPL], ys[CPL];
    float dot = 0.f, ff = 0.f, aa = 0.f;
    #pragma unroll
    for (int i = 0; i < CPL; ++i) {
        const float x = bf2f(fr[lane + i * 64]);
        const float y = bf2f(ar[lane + i * 64]);
        xs[i] = x; ys[i] = y;
        dot = fmaf(x, y, dot);
        ff  = fmaf(x, x, ff);
        aa  = fmaf(y, y, aa);
    }
    #pragma unroll
    for (int msk = 1; msk < 64; msk <<= 1) {
        dot += __shfl_xor(dot, msk);
        ff  += __shfl_xor(ff,  msk);
        aa  += __shfl_xor(aa,  msk);
    }
    const float m = dot / fmaxf(sqrtf(ff) * sqrtf(aa), 1e-8f);
    unsigned short* orow = att + (size_t)idx * 2 * C;
    #pragma unroll
    for (int i = 0; i < CPL; ++i) {
        orow[lane + i * 64]     = f2bf(xs[i] * m);
        orow[C + lane + i * 64] = f2bf(ys[i] * m);
    }
}

// ---------------------------------------------------------------------------
// rd-path loader (conv1/conv2)
// ---------------------------------------------------------------------------
struct PlainB16 {
    const uint4* x; int N; int C8;
    struct Ref { int o; };
    __device__ __forceinline__ Ref prep(int t, int node) const {
        return { (int)(((size_t)t * N + node) * C8) };
    }
    __device__ __forceinline__ uint4 chunk(const Ref& r, int c8) const {
        return x[r.o + c8];
    }
};

// ---------------------------------------------------------------------------
// weight prep:
//  rd layout  : Wt[d][kc]            (conv1/conv2)
//  split layout: Wt[k*CO+d][c-sub]   (conv7/conv8 halves)
// ---------------------------------------------------------------------------
__global__ __launch_bounds__(256) void wprep_all_kernel(
    const float* __restrict__ W1f, const float* __restrict__ W1a,
    const float* __restrict__ W2f, const float* __restrict__ W2a,
    const float* __restrict__ W7,  const float* __restrict__ W8,
    unsigned short* __restrict__ Wt1f, unsigned short* __restrict__ Wt1a,
    unsigned short* __restrict__ Wt2f, unsigned short* __restrict__ Wt2a,
    unsigned short* __restrict__ Wt7a, unsigned short* __restrict__ Wt7b,
    unsigned short* __restrict__ Wt8a, unsigned short* __restrict__ Wt8b)
{
    int idx = blockIdx.x * 256 + threadIdx.x;
    if (idx < 143360) {   // rd weights
        const float* W; unsigned short* Wt; int KCv, CO;
        if (idx < 14336)       { W = W1f; Wt = Wt1f; KCv = 224;  CO = 64;  }
        else if (idx < 28672)  { idx -= 14336; W = W1a; Wt = Wt1a; KCv = 224; CO = 64; }
        else if (idx < 86016)  { idx -= 28672; W = W2f; Wt = Wt2f; KCv = 448; CO = 128; }
        else                   { idx -= 86016; W = W2a; Wt = Wt2a; KCv = 448; CO = 128; }
        const int d = idx / KCv, kc = idx - d * KCv;
        Wt[idx] = f2bf(W[(size_t)kc * CO + d]);
    } else if (idx < 258048) {   // Wt7a [448][256] <- W7[k][c<256][d]
        const int l = idx - 143360;
        const int kd = l >> 8, c = l & 255;
        const int k = kd >> 6, d = kd & 63;
        Wt7a[l] = f2bf(W7[((size_t)k * 384 + c) * 64 + d]);
    } else if (idx < 315392) {   // Wt7b [448][128] <- W7[k][256+c][d]
        const int l = idx - 258048;
        const int kd = l >> 7, c = l & 127;
        const int k = kd >> 6, d = kd & 63;
        Wt7b[l] = f2bf(W7[((size_t)k * 384 + 256 + c) * 64 + d]);
    } else if (idx < 329728) {   // Wt8a [224][64] <- W8[k][c<64][d]
        const int l = idx - 315392;
        const int kd = l >> 6, c = l & 63;
        const int k = kd >> 5, d = kd & 31;
        Wt8a[l] = f2bf(W8[((size_t)k * 128 + c) * 32 + d]);
    } else if (idx < 344064) {   // Wt8b [224][64] <- W8[k][64+c][d]
        const int l = idx - 329728;
        const int kd = l >> 6, c = l & 63;
        const int k = kd >> 5, d = kd & 31;
        Wt8b[l] = f2bf(W8[((size_t)k * 128 + 64 + c) * 32 + d]);
    }
}

// ---------------------------------------------------------------------------
// Pure streaming GEMM: Z[m][nd] = sum_c A[m][c] * Wt[nd][c].
// A [M][CINs] bf16 rows read fully coalesced (no indirection). 4 waves of
// 32x32 tiles; BK=64, XOR-swizzled LDS; C-tile written back through LDS as
// coalesced uint4 (full 128B lines) to avoid partial-line write amplification.
// ---------------------------------------------------------------------------
template<int CINs, int NDIM, int BM, int BN>
__global__ __launch_bounds__(256) void gemm_c_kernel(
    const unsigned short* __restrict__ A, int M,
    const unsigned short* __restrict__ Wt,
    unsigned short* __restrict__ Z)
{
    constexpr int KSTEPS = CINs / 64;
    constexpr int NT    = NDIM / BN;
    constexpr int U4R   = 8;                 // 16B chunks per 64-col slice
    constexpr int WGR_N = BN / 32;
    constexpr int WGR_M = 4 / WGR_N;
    constexpr int VPTA  = BM * U4R / 256;
    constexpr int VPTW  = BN * U4R / 256;
    static_assert(BM == WGR_M * 32 && CINs % 64 == 0 && VPTW >= 1);

    __shared__ __align__(16) unsigned short As[BM * 64];
    __shared__ __align__(16) unsigned short Ws[BN * 64];

    const int tile_m = blockIdx.x / NT;
    const int tile_n = blockIdx.x % NT;
    const int m0 = tile_m * BM;

    const int tid = threadIdx.x, lane = tid & 63, wave = tid >> 6;
    const int wr = wave / WGR_N, wc = wave % WGR_N;
    const int l15 = lane & 15, lhi = lane >> 4;

    f32x4 acc[2][2] = {};

    for (int ks = 0; ks < KSTEPS; ++ks) {
        uint4 av[VPTA];
        #pragma unroll
        for (int v = 0; v < VPTA; ++v) {
            const int g = tid + v * 256, row = g >> 3, c8 = g & 7;
            av[v] = *reinterpret_cast<const uint4*>(
                A + (size_t)min(m0 + row, M - 1) * CINs + ks * 64 + c8 * 8);
        }
        uint4 wv[VPTW];
        #pragma unroll
        for (int v = 0; v < VPTW; ++v) {
            const int g = tid + v * 256, d = g >> 3, c8 = g & 7;
            wv[v] = *reinterpret_cast<const uint4*>(
                Wt + (size_t)(tile_n * BN + d) * CINs + ks * 64 + c8 * 8);
        }

        __syncthreads();
        #pragma unroll
        for (int v = 0; v < VPTA; ++v) {
            const int g = tid + v * 256, row = g >> 3, c8 = g & 7;
            *reinterpret_cast<uint4*>(&As[(row * 64 + c8 * 8) ^ ((row & 7) << 3)]) = av[v];
        }
        #pragma unroll
        for (int v = 0; v < VPTW; ++v) {
            const int g = tid + v * 256, d = g >> 3, c8 = g & 7;
            *reinterpret_cast<uint4*>(&Ws[(d * 64 + c8 * 8) ^ ((d & 7) << 3)]) = wv[v];
        }
        __syncthreads();

        #pragma unroll
        for (int kk2 = 0; kk2 < 2; ++kk2) {
            const int kb = kk2 * 32 + lhi * 8;
            bf16x8 a[2], b[2];
            #pragma unroll
            for (int m = 0; m < 2; ++m) {
                const int row = wr * 32 + m * 16 + l15;
                a[m] = *reinterpret_cast<const bf16x8*>(&As[(row * 64 + kb) ^ ((row & 7) << 3)]);
            }
            #pragma unroll
            for (int n = 0; n < 2; ++n) {
                const int col = wc * 32 + n * 16 + l15;
                b[n] = *reinterpret_cast<const bf16x8*>(&Ws[(col * 64 + kb) ^ ((col & 7) << 3)]);
            }
            #pragma unroll
            for (int m = 0; m < 2; ++m)
                #pragma unroll
                for (int n = 0; n < 2; ++n)
                    acc[m][n] = __builtin_amdgcn_mfma_f32_16x16x32_bf16(a[m], b[n], acc[m][n], 0, 0, 0);
        }
    }

    // coalesced C-writeback through LDS (reuse As; BM*BN <= BM*64)
    __syncthreads();
    unsigned short* Cs = As;
    #pragma unroll
    for (int n = 0; n < 2; ++n) {
        const int col = wc * 32 + n * 16 + l15;
        #pragma unroll
        for (int m = 0; m < 2; ++m)
            #pragma unroll
            for (int i = 0; i < 4; ++i)
                Cs[(wr * 32 + m * 16 + lhi * 4 + i) * BN + col] = f2bf(acc[m][n][i]);
    }
    __syncthreads();
    constexpr int RPT = BN / 8;              // uint4 per row
    constexpr int CV  = BM * BN / 8 / 256;   // uint4 per thread (=2)
    #pragma unroll
    for (int v = 0; v < CV; ++v) {
        const int g = tid + v * 256, row = g / RPT, c8 = g % RPT;
        const int grow = m0 + row;
        if (grow < M)
            *reinterpret_cast<uint4*>(&Z[(size_t)grow * NDIM + tile_n * BN + c8 * 8]) =
                *reinterpret_cast<const uint4*>(&Cs[row * BN + c8 * 8]);
    }
}

// ---------------------------------------------------------------------------
// dual-source gather-reduce epilogue:
// out[t,n,:] = relu(b + sum_k Zu[t, up[nb_k], k-slice] + Zb[t, nb_k, k-slice])
// ---------------------------------------------------------------------------
template<int COUT>
__global__ __launch_bounds__(256) void epi_dual_kernel(
    const unsigned short* __restrict__ Zu, const unsigned short* __restrict__ Zb,
    const int* __restrict__ up, const int* __restrict__ neigh,
    int N, int Nu, const float* __restrict__ bias, unsigned short* __restrict__ out)
{
    constexpr int ND = K * COUT;
    constexpr int C8 = COUT / 8;
    const int idx = blockIdx.x * 256 + threadIdx.x;
    if (idx >= T * N * C8) return;
    const int c8 = idx % C8;
    const int n  = (idx / C8) % N;
    const int t  = idx / (C8 * N);
    const int* nb = neigh + n * K;

    float s[8];
    #pragma unroll
    for (int j = 0; j < 8; ++j) s[j] = bias[c8 * 8 + j];
    #pragma unroll
    for (int k = 0; k < K; ++k) {
        const int jn = nb[k];
        const int ju = up[jn];
        const uint4 vu = *reinterpret_cast<const uint4*>(
            &Zu[((size_t)t * Nu + ju) * ND + k * COUT + c8 * 8]);
        const uint4 vb = *reinterpret_cast<const uint4*>(
            &Zb[((size_t)t * N + jn) * ND + k * COUT + c8 * 8]);
        const unsigned short* pu = reinterpret_cast<const unsigned short*>(&vu);
        const unsigned short* pb = reinterpret_cast<const unsigned short*>(&vb);
        #pragma unroll
        for (int j = 0; j < 8; ++j) s[j] += bf2f(pu[j]) + bf2f(pb[j]);
    }
    unsigned short o[8];
    #pragma unroll
    for (int j = 0; j < 8; ++j) o[j] = f2bf(fmaxf(s[j], 0.f));
    *reinterpret_cast<uint4*>(&out[((size_t)t * N + n) * COUT + c8 * 8]) =
        *reinterpret_cast<const uint4*>(o);
}

// ---------------------------------------------------------------------------
// rd path (conv1/conv2): per-wave 32x32 MFMA tile (r6, unchanged)
// ---------------------------------------------------------------------------
template<int CIN, int COUT, class Loader>
__device__ __forceinline__ void sconv_tile(
    const Loader& ldr, const int* __restrict__ neigh, int N, int t,
    int tile_m, int tile_n,
    const unsigned short* __restrict__ Wt, const float* __restrict__ bias,
    unsigned short* __restrict__ out)
{
    constexpr int KC     = K * CIN;
    constexpr int CHUNKS = CIN / 32;
    constexpr int STEPS  = K * CHUNKS;
    constexpr int D      = STEPS < 3 ? STEPS : 3;

    const int lane = threadIdx.x & 63;
    const int l15 = lane & 15, lhi = lane >> 4;

    const int r0 = tile_m * 32 + l15;
    const int row0 = min(r0, N - 1), row1 = min(r0 + 16, N - 1);

    typename Loader::Ref ref0[K], ref1[K];
    #pragma unroll
    for (int k = 0; k < K; ++k) {
        ref0[k] = ldr.prep(t, neigh[row0 * K + k]);
        ref1[k] = ldr.prep(t, neigh[row1 * K + k]);
    }

    const int col0 = tile_n * 32 + l15;
    const unsigned short* w0p = Wt + (size_t)col0 * KC + lhi * 8;
    const unsigned short* w1p = w0p + (size_t)16 * KC;

    uint4 qa0[D], qa1[D], qb0[D], qb1[D];

    auto issue = [&](int s, int slot) {
        const int k = s / CHUNKS, c = s - k * CHUNKS;
        const int c8 = c * 4 + lhi;
        qa0[slot] = ldr.chunk(ref0[k], c8);
        qa1[slot] = ldr.chunk(ref1[k], c8);
        qb0[slot] = *reinterpret_cast<const uint4*>(w0p + k * CIN + c * 32);
        qb1[slot] = *reinterpret_cast<const uint4*>(w1p + k * CIN + c * 32);
    };

    f32x4 acc[2][2] = {};

    #pragma unroll
    for (int s = 0; s < D; ++s) issue(s, s);
    __builtin_amdgcn_sched_barrier(0);

    #pragma unroll
    for (int s = 0; s < STEPS; ++s) {
        const int slot = s % D;
        const bf16x8 a0 = __builtin_bit_cast(bf16x8, qa0[slot]);
        const bf16x8 a1 = __builtin_bit_cast(bf16x8, qa1[slot]);
        const bf16x8 b0 = __builtin_bit_cast(bf16x8, qb0[slot]);
        const bf16x8 b1 = __builtin_bit_cast(bf16x8, qb1[slot]);
        acc[0][0] = __builtin_amdgcn_mfma_f32_16x16x32_bf16(a0, b0, acc[0][0], 0, 0, 0);
        acc[0][1] = __builtin_amdgcn_mfma_f32_16x16x32_bf16(a0, b1, acc[0][1], 0, 0, 0);
        acc[1][0] = __builtin_amdgcn_mfma_f32_16x16x32_bf16(a1, b0, acc[1][0], 0, 0, 0);
        acc[1][1] = __builtin_amdgcn_mfma_f32_16x16x32_bf16(a1, b1, acc[1][1], 0, 0, 0);
        if (s + D < STEPS) issue(s + D, slot);
        __builtin_amdgcn_sched_barrier(0);
    }

    #pragma unroll
    for (int n = 0; n < 2; ++n) {
        const int gcol = tile_n * 32 + n * 16 + l15;
        const float bv = bias[gcol];
        #pragma unroll
        for (int m = 0; m < 2; ++m) {
            #pragma unroll
            for (int i = 0; i < 4; ++i) {
                const int grow = tile_m * 32 + m * 16 + lhi * 4 + i;
                if (grow < N)
                    out[((size_t)t * N + grow) * COUT + gcol] =
                        f2bf(fmaxf(acc[m][n][i] + bv, 0.f));
            }
        }
    }
}

template<int CIN, int COUT, class Loader>
__global__ __launch_bounds__(64, 2) void sconv_rd2_kernel(
    Loader lf, Loader la, const int* __restrict__ neigh, int N, int U,
    const unsigned short* __restrict__ Wtf, const unsigned short* __restrict__ Wta,
    const float* __restrict__ bf_, const float* __restrict__ ba_,
    unsigned short* __restrict__ of_, unsigned short* __restrict__ oa_)
{
    constexpr int TN = COUT / 32;
    const int xcd = blockIdx.x & 7;
    int idx = blockIdx.x >> 3;
    const int sel = idx & 1; idx >>= 1;
    const int hi = (idx >= U) ? 1 : 0;
    const int t  = 2 * xcd + hi;
    const int w  = idx - hi * U;
    const Loader L = sel ? la : lf;
    const unsigned short* Wt = sel ? Wta : Wtf;
    const float* bias = sel ? ba_ : bf_;
    unsigned short* out = sel ? oa_ : of_;
    sconv_tile<CIN, COUT, Loader>(L, neigh, N, t, w / TN, w % TN, Wt, bias, out);
}

// ---------------------------------------------------------------------------
// conv9: logits fp32 from bf16 cv8
// ---------------------------------------------------------------------------
__global__ __launch_bounds__(256) void conv9_kernel(
    const unsigned short* __restrict__ cv8, const int* __restrict__ neigh5,
    const float* __restrict__ W9, const float* __restrict__ b9,
    float* __restrict__ logits)
{
    const int idx = blockIdx.x * 256 + threadIdx.x;
    if (idx >= T * n5) return;
    const int n = idx % n5;
    const int t = idx / n5;
    float acc = b9[0];
    const int* nb = neigh5 + n * K;
    #pragma unroll
    for (int k = 0; k < K; ++k) {
        const uint4* row = reinterpret_cast<const uint4*>(cv8 + ((size_t)t * n5 + nb[k]) * 32);
        const float* wk = W9 + k * 32;
        #pragma unroll
        for (int c4 = 0; c4 < 4; ++c4) {
            const uint4 v = row[c4];
            const unsigned short* s = reinterpret_cast<const unsigned short*>(&v);
            #pragma unroll
            for (int jj = 0; jj < 8; ++jj)
                acc = fmaf(bf2f(s[jj]), wk[c4 * 8 + jj], acc);
        }
    }
    logits[idx] = acc;
}

// ---------------------------------------------------------------------------
// softmax
// ---------------------------------------------------------------------------
__global__ __launch_bounds__(1024) void softmax_kernel(
    const float* __restrict__ logits, float* __restrict__ out)
{
    const int t = blockIdx.x, tid = threadIdx.x;
    const float* x = logits + (size_t)t * n5;
    float* y = out + (size_t)t * n5;
    __shared__ float redmax[16], redsum[16];

    float mx = -FLT_MAX;
    for (int i = tid; i < n5; i += 1024) mx = fmaxf(mx, x[i]);
    #pragma unroll
    for (int m = 1; m < 64; m <<= 1) mx = fmaxf(mx, __shfl_xor(mx, m));
    if ((tid & 63) == 0) redmax[tid >> 6] = mx;
    __syncthreads();
    mx = redmax[0];
    #pragma unroll
    for (int i = 1; i < 16; ++i) mx = fmaxf(mx, redmax[i]);

    float s = 0.f;
    for (int i = tid; i < n5; i += 1024) s += expf(x[i] - mx);
    #pragma unroll
    for (int m = 1; m < 64; m <<= 1) s += __shfl_xor(s, m);
    if ((tid & 63) == 0) redsum[tid >> 6] = s;
    __syncthreads();
    s = 0.f;
    #pragma unroll
    for (int i = 0; i < 16; ++i) s += redsum[i];

    for (int i = tid; i < n5; i += 1024) y[i] = expf(x[i] - mx) / s;
}

// ---------------------------------------------------------------------------
extern "C" void kernel_launch(void* const* d_in, const int* in_sizes, int n_in,
                              void* d_out, int out_size, void* d_ws, size_t ws_size,
                              hipStream_t stream)
{
    const float* frame = (const float*)d_in[0];
    const float* aem   = (const float*)d_in[1];
    const float* W0f = (const float*)d_in[2];
    const float* b0f = (const float*)d_in[3];
    const float* W0a = (const float*)d_in[4];
    const float* b0a = (const float*)d_in[5];
    const float* W1f = (const float*)d_in[6];
    const float* b1f = (const float*)d_in[7];
    const float* W1a = (const float*)d_in[8];
    const float* b1a = (const float*)d_in[9];
    const float* W2f = (const float*)d_in[10];
    const float* b2f = (const float*)d_in[11];
    const float* W2a = (const float*)d_in[12];
    const float* b2a = (const float*)d_in[13];
    const float* W7  = (const float*)d_in[14];
    const float* b7  = (const float*)d_in[15];
    const float* W8  = (const float*)d_in[16];
    const float* b8  = (const float*)d_in[17];
    const float* W9  = (const float*)d_in[18];
    const float* b9  = (const float*)d_in[19];
    const int* neigh5 = (const int*)d_in[20];
    const int* neigh4 = (const int*)d_in[21];
    const int* neigh3 = (const int*)d_in[22];
    const int* pool5  = (const int*)d_in[23];
    const int* pool4  = (const int*)d_in[24];
    const int* up4    = (const int*)d_in[25];
    const int* up5    = (const int*)d_in[26];

    unsigned short* wsu = (unsigned short*)d_ws;
    size_t off = 0;
    auto ua = [&](size_t n) {
        unsigned short* p = wsu + off; off += (n + 7) & ~(size_t)7; return p;
    };
    unsigned short* c0f  = ua((size_t)T * n5 * 32);
    unsigned short* c0a  = ua((size_t)T * n5 * 32);
    unsigned short* att0 = ua((size_t)T * n5 * 64);
    unsigned short* p0f  = ua((size_t)T * n4 * 32);
    unsigned short* p0a  = ua((size_t)T * n4 * 32);
    unsigned short* c1f  = ua((size_t)T * n4 * 64);
    unsigned short* c1a  = ua((size_t)T * n4 * 64);
    unsigned short* att1 = ua((size_t)T * n4 * 128);
    unsigned short* p1f  = ua((size_t)T * n3 * 64);
    unsigned short* p1a  = ua((size_t)T * n3 * 64);
    unsigned short* c2f  = ua((size_t)T * n3 * 128);
    unsigned short* c2a  = ua((size_t)T * n3 * 128);
    unsigned short* att2 = ua((size_t)T * n3 * 256);
    unsigned short* cv7  = ua((size_t)T * n4 * 64);
    unsigned short* cv8  = ua((size_t)T * n5 * 32);
    unsigned short* Wt1f = ua((size_t)64 * 224);
    unsigned short* Wt1a = ua((size_t)64 * 224);
    unsigned short* Wt2f = ua((size_t)128 * 448);
    unsigned short* Wt2a = ua((size_t)128 * 448);
    unsigned short* Wt7a = ua((size_t)448 * 256);
    unsigned short* Wt7b = ua((size_t)448 * 128);
    unsigned short* Wt8a = ua((size_t)224 * 64);
    unsigned short* Wt8b = ua((size_t)224 * 64);
    // Z arena (phase 1: Z2+Zb7, phase 2 overlays: Z7s+Zb8)
    unsigned short* arena = ua((size_t)T * n4 * 224 + (size_t)T * n5 * 224);
    unsigned short* Z2  = arena;                               // [T*n3][448]
    unsigned short* Zb7 = arena + (size_t)T * n3 * 448;        // [T*n4][448]
    unsigned short* Z7s = arena;                               // [T*n4][224]
    unsigned short* Zb8 = arena + (size_t)T * n4 * 224;        // [T*n5][224]
    float* lgt = (float*)(wsu + ((off + 1) & ~(size_t)1));

    wprep_all_kernel<<<1344, 256, 0, stream>>>(
        W1f, W1a, W2f, W2a, W7, W8,
        Wt1f, Wt1a, Wt2f, Wt2a, Wt7a, Wt7b, Wt8a, Wt8b);

    conv0_kernel<<<T * ((n5 + 7) / 8), 256, 0, stream>>>(
        frame, aem, W0f, b0f, W0a, b0a, neigh5, c0f, c0a, att0);

    {
        const int thr = T * n4 * (32 / 8);
        pool_kernel<32><<<(thr + 255) / 256, 256, 0, stream>>>(c0f, pool5, n5, n4, p0f);
        pool_kernel<32><<<(thr + 255) / 256, 256, 0, stream>>>(c0a, pool5, n5, n4, p0a);
    }

    // conv1 f+a fused rd: U=162
    {
        constexpr int U = 81 * 2;
        sconv_rd2_kernel<32, 64><<<8 * 4 * U, 64, 0, stream>>>(
            PlainB16{(const uint4*)p0f, n4, 4}, PlainB16{(const uint4*)p0a, n4, 4},
            neigh4, n4, U, Wt1f, Wt1a, b1f, b1a, c1f, c1a);
    }
    cosatt_kernel<64, n4><<<(T * n4 + 3) / 4, 256, 0, stream>>>(c1f, c1a, att1);

    {
        const int thr = T * n3 * (64 / 8);
        pool_kernel<64><<<(thr + 255) / 256, 256, 0, stream>>>(c1f, pool4, n4, n3, p1f);
        pool_kernel<64><<<(thr + 255) / 256, 256, 0, stream>>>(c1a, pool4, n4, n3, p1a);
    }

    // conv2 f+a fused rd: U=84
    {
        constexpr int U = 21 * 4;
        sconv_rd2_kernel<64, 128><<<8 * 4 * U, 64, 0, stream>>>(
            PlainB16{(const uint4*)p1f, n3, 8}, PlainB16{(const uint4*)p1a, n3, 8},
            neigh3, n3, U, Wt2f, Wt2a, b2f, b2a, c2f, c2a);
    }
    cosatt_kernel<128, n3><<<(T * n3 + 3) / 4, 256, 0, stream>>>(c2f, c2a, att2);

    // conv7 = two streaming GEMMs + dual gather-reduce
    {
        constexpr int M2 = T * n3;            // 10272
        constexpr int Mb = T * n4;            // 40992
        gemm_c_kernel<256, 448, 64, 64><<<((M2 + 63) / 64) * 7, 256, 0, stream>>>(
            att2, M2, Wt7a, Z2);
        gemm_c_kernel<128, 448, 64, 64><<<((Mb + 63) / 64) * 7, 256, 0, stream>>>(
            att1, Mb, Wt7b, Zb7);
        const int thr = T * n4 * 8;
        epi_dual_kernel<64><<<(thr + 255) / 256, 256, 0, stream>>>(
            Z2, Zb7, up4, neigh4, n4, n3, b7, cv7);
    }

    // conv8 = two streaming GEMMs + dual gather-reduce
    {
        constexpr int Ms = T * n4;            // 40992
        constexpr int Mb = T * n5;            // 163872
        gemm_c_kernel<64, 224, 128, 32><<<((Ms + 127) / 128) * 7, 256, 0, stream>>>(
            cv7, Ms, Wt8a, Z7s);
        gemm_c_kernel<64, 224, 128, 32><<<((Mb + 127) / 128) * 7, 256, 0, stream>>>(
            att0, Mb, Wt8b, Zb8);
        const int thr = T * n5 * 4;
        epi_dual_kernel<32><<<(thr + 255) / 256, 256, 0, stream>>>(
            Z7s, Zb8, up5, neigh5, n5, n4, b8, cv8);
    }

    conv9_kernel<<<(T * n5 + 255) / 256, 256, 0, stream>>>(cv8, neigh5, W9, b9, lgt);

    softmax_kernel<<<T, 1024, 0, stream>>>(lgt, (float*)d_out);
}

// Round 9
// 346.322 us; speedup vs baseline: 1.0584x; 1.0584x over previous
//
#include <hip/hip_runtime.h>
#include <cfloat>
#include <cstdint>

// Model2c round 9: r8's split streaming GEMMs kept, but Z is PLANE-MAJOR
// [K][M][COUT] so every GEMM block writes one contiguous 8KB full-line region
// (r8's [M][K*COUT] layout caused 2.9x write amplification + RMW fetches:
// 64B half-lines shared between blocks). Epilogues read plane-major and are
// t<->XCD pinned so per-t Z planes stay L2-resident across 7x neighbor reuse.
//   conv7: Z2[k][T*n3][64], Zb7[k][T*n4][64];
//          cv7[n] = relu(b7 + sum_k Z2[k][up4[nb_k]] + Zb7[k][nb_k])
//   conv8: Z7s[k][T*n4][32], Zb8[k][T*n5][32];
//          cv8[n] = relu(b8 + sum_k Z7s[k][up5[nb_k]] + Zb8[k][nb_k])
// conv1/conv2 keep the r6 reg-direct path. ws ~191 MB.

constexpr int T  = 16;
constexpr int n5 = 10242, n4 = 2562, n3 = 642;
constexpr int K  = 7;

using bf16x8 = __attribute__((ext_vector_type(8))) short;
using f32x4  = __attribute__((ext_vector_type(4))) float;

static __device__ __forceinline__ float bf2f(unsigned short u) {
    return __uint_as_float((unsigned)u << 16);
}
static __device__ __forceinline__ unsigned short f2bf(float x) {
    unsigned u = __float_as_uint(x);
    u += 0x7FFF + ((u >> 16) & 1);
    return (unsigned short)(u >> 16);
}

// ---------------------------------------------------------------------------
// conv0: c0f/c0a (bf16) + fused cos -> att0 = bf16[c0f*m | c0a*m]
// ---------------------------------------------------------------------------
__global__ __launch_bounds__(256) void conv0_kernel(
    const float* __restrict__ frame, const float* __restrict__ aem,
    const float* __restrict__ W0f, const float* __restrict__ b0f,
    const float* __restrict__ W0a, const float* __restrict__ b0a,
    const int* __restrict__ neigh5,
    unsigned short* __restrict__ c0f, unsigned short* __restrict__ c0a,
    unsigned short* __restrict__ att0)
{
    const int g = threadIdx.x >> 5;
    const int d = threadIdx.x & 31;
    const int per_t = (n5 + 7) / 8;
    const int t = blockIdx.x / per_t;
    const int n = (blockIdx.x % per_t) * 8 + g;
    if (n >= n5) return;

    float accf = b0f[d];
    float acca = b0a[d];
    const int* nb = neigh5 + n * K;
    #pragma unroll
    for (int k = 0; k < K; ++k) {
        const int j = nb[k];
        const float* fr = frame + ((size_t)t * n5 + j) * 3;
        const float av = aem[(size_t)t * n5 + j];
        accf = fmaf(fr[0], W0f[(k * 3 + 0) * 32 + d], accf);
        accf = fmaf(fr[1], W0f[(k * 3 + 1) * 32 + d], accf);
        accf = fmaf(fr[2], W0f[(k * 3 + 2) * 32 + d], accf);
        acca = fmaf(av, W0a[k * 32 + d], acca);
    }
    accf = fmaxf(accf, 0.f);
    acca = fmaxf(acca, 0.f);

    float dot = accf * acca, ff = accf * accf, aa = acca * acca;
    #pragma unroll
    for (int m = 1; m < 32; m <<= 1) {
        dot += __shfl_xor(dot, m, 32);
        ff  += __shfl_xor(ff,  m, 32);
        aa  += __shfl_xor(aa,  m, 32);
    }
    const float mm = dot / fmaxf(sqrtf(ff) * sqrtf(aa), 1e-8f);
    const size_t base = ((size_t)t * n5 + n) * 32;
    c0f[base + d] = f2bf(accf);
    c0a[base + d] = f2bf(acca);
    const size_t abase = ((size_t)t * n5 + n) * 64;
    att0[abase + d]      = f2bf(accf * mm);
    att0[abase + 32 + d] = f2bf(acca * mm);
}

// ---------------------------------------------------------------------------
// pool (bf16 -> bf16)
// ---------------------------------------------------------------------------
template<int C>
__global__ __launch_bounds__(256) void pool_kernel(
    const unsigned short* __restrict__ in, const int* __restrict__ pidx,
    int Nin, int Nout, unsigned short* __restrict__ out)
{
    constexpr int C8 = C / 8;
    const int idx = blockIdx.x * 256 + threadIdx.x;
    if (idx >= T * Nout * C8) return;
    const int c8 = idx % C8;
    const int n  = (idx / C8) % Nout;
    const int t  = idx / (C8 * Nout);
    const int* pp = pidx + n * K;
    float m[8];
    #pragma unroll
    for (int j = 0; j < 8; ++j) m[j] = -FLT_MAX;
    #pragma unroll
    for (int k = 0; k < K; ++k) {
        const uint4 v = reinterpret_cast<const uint4*>(in)[((size_t)t * Nin + pp[k]) * C8 + c8];
        const unsigned short* s = reinterpret_cast<const unsigned short*>(&v);
        #pragma unroll
        for (int j = 0; j < 8; ++j) m[j] = fmaxf(m[j], bf2f(s[j]));
    }
    unsigned short o[8];
    #pragma unroll
    for (int j = 0; j < 8; ++j) o[j] = f2bf(m[j]);
    reinterpret_cast<uint4*>(out)[((size_t)t * Nout + n) * C8 + c8] =
        *reinterpret_cast<const uint4*>(o);
}

// ---------------------------------------------------------------------------
// cosatt: m = cos(f,a); att = bf16[f*m | a*m]
// ---------------------------------------------------------------------------
template<int C, int NN>
__global__ __launch_bounds__(256) void cosatt_kernel(
    const unsigned short* __restrict__ f, const unsigned short* __restrict__ a,
    unsigned short* __restrict__ att)
{
    constexpr int CPL = C / 64;
    const int w = threadIdx.x >> 6, lane = threadIdx.x & 63;
    const int idx = blockIdx.x * 4 + w;
    if (idx >= T * NN) return;
    const unsigned short* fr = f + (size_t)idx * C;
    const unsigned short* ar = a + (size_t)idx * C;
    float xs[CPL], ys[CPL];
    float dot = 0.f, ff = 0.f, aa = 0.f;
    #pragma unroll
    for (int i = 0; i < CPL; ++i) {
        const float x = bf2f(fr[lane + i * 64]);
        const float y = bf2f(ar[lane + i * 64]);
        xs[i] = x; ys[i] = y;
        dot = fmaf(x, y, dot);
        ff  = fmaf(x, x, ff);
        aa  = fmaf(y, y, aa);
    }
    #pragma unroll
    for (int msk = 1; msk < 64; msk <<= 1) {
        dot += __shfl_xor(dot, msk);
        ff  += __shfl_xor(ff,  msk);
        aa  += __shfl_xor(aa,  msk);
    }
    const float m = dot / fmaxf(sqrtf(ff) * sqrtf(aa), 1e-8f);
    unsigned short* orow = att + (size_t)idx * 2 * C;
    #pragma unroll
    for (int i = 0; i < CPL; ++i) {
        orow[lane + i * 64]     = f2bf(xs[i] * m);
        orow[C + lane + i * 64] = f2bf(ys[i] * m);
    }
}

// ---------------------------------------------------------------------------
// rd-path loader (conv1/conv2)
// ---------------------------------------------------------------------------
struct PlainB16 {
    const uint4* x; int N; int C8;
    struct Ref { int o; };
    __device__ __forceinline__ Ref prep(int t, int node) const {
        return { (int)(((size_t)t * N + node) * C8) };
    }
    __device__ __forceinline__ uint4 chunk(const Ref& r, int c8) const {
        return x[r.o + c8];
    }
};

// ---------------------------------------------------------------------------
// weight prep:
//  rd layout   : Wt[d][kc]            (conv1/conv2)
//  split layout: Wt[k*CO+d][c-sub]    (conv7/conv8 halves)
// ---------------------------------------------------------------------------
__global__ __launch_bounds__(256) void wprep_all_kernel(
    const float* __restrict__ W1f, const float* __restrict__ W1a,
    const float* __restrict__ W2f, const float* __restrict__ W2a,
    const float* __restrict__ W7,  const float* __restrict__ W8,
    unsigned short* __restrict__ Wt1f, unsigned short* __restrict__ Wt1a,
    unsigned short* __restrict__ Wt2f, unsigned short* __restrict__ Wt2a,
    unsigned short* __restrict__ Wt7a, unsigned short* __restrict__ Wt7b,
    unsigned short* __restrict__ Wt8a, unsigned short* __restrict__ Wt8b)
{
    int idx = blockIdx.x * 256 + threadIdx.x;
    if (idx < 143360) {   // rd weights
        const float* W; unsigned short* Wt; int KCv, CO;
        if (idx < 14336)       { W = W1f; Wt = Wt1f; KCv = 224;  CO = 64;  }
        else if (idx < 28672)  { idx -= 14336; W = W1a; Wt = Wt1a; KCv = 224; CO = 64; }
        else if (idx < 86016)  { idx -= 28672; W = W2f; Wt = Wt2f; KCv = 448; CO = 128; }
        else                   { idx -= 86016; W = W2a; Wt = Wt2a; KCv = 448; CO = 128; }
        const int d = idx / KCv, kc = idx - d * KCv;
        Wt[idx] = f2bf(W[(size_t)kc * CO + d]);
    } else if (idx < 258048) {   // Wt7a [448][256] <- W7[k][c<256][d]
        const int l = idx - 143360;
        const int kd = l >> 8, c = l & 255;
        const int k = kd >> 6, d = kd & 63;
        Wt7a[l] = f2bf(W7[((size_t)k * 384 + c) * 64 + d]);
    } else if (idx < 315392) {   // Wt7b [448][128] <- W7[k][256+c][d]
        const int l = idx - 258048;
        const int kd = l >> 7, c = l & 127;
        const int k = kd >> 6, d = kd & 63;
        Wt7b[l] = f2bf(W7[((size_t)k * 384 + 256 + c) * 64 + d]);
    } else if (idx < 329728) {   // Wt8a [224][64] <- W8[k][c<64][d]
        const int l = idx - 315392;
        const int kd = l >> 6, c = l & 63;
        const int k = kd >> 5, d = kd & 31;
        Wt8a[l] = f2bf(W8[((size_t)k * 128 + c) * 32 + d]);
    } else if (idx < 344064) {   // Wt8b [224][64] <- W8[k][64+c][d]
        const int l = idx - 329728;
        const int kd = l >> 6, c = l & 63;
        const int k = kd >> 5, d = kd & 31;
        Wt8b[l] = f2bf(W8[((size_t)k * 128 + 64 + c) * 32 + d]);
    }
}

// ---------------------------------------------------------------------------
// Plane-major streaming GEMM: Z[k][m][d] = sum_c A[m][c] * Wt[k*BN+d][c].
// grid = Mtiles * K; block (tile_m, k) writes ONE contiguous BM*BN*2-byte
// region (full cache lines, exclusively owned) -> no write amplification.
// ---------------------------------------------------------------------------
template<int CINs, int BN, int BM>
__global__ __launch_bounds__(256) void gemm_p_kernel(
    const unsigned short* __restrict__ A, int M,
    const unsigned short* __restrict__ Wt,
    unsigned short* __restrict__ Z)
{
    constexpr int KSTEPS = CINs / 64;
    constexpr int U4R   = 8;
    constexpr int WGR_N = BN / 32;
    constexpr int WGR_M = 4 / WGR_N;
    constexpr int VPTA  = BM * U4R / 256;
    constexpr int VPTW  = BN * U4R / 256 > 0 ? BN * U4R / 256 : 1;
    static_assert(BM == WGR_M * 32 && CINs % 64 == 0 && VPTW >= 1);

    __shared__ __align__(16) unsigned short As[BM * 64];
    __shared__ __align__(16) unsigned short Ws[BN * 64];

    const int tile_m = blockIdx.x / K;
    const int kpl    = blockIdx.x % K;
    const int m0 = tile_m * BM;

    const int tid = threadIdx.x, lane = tid & 63, wave = tid >> 6;
    const int wr = wave / WGR_N, wc = wave % WGR_N;
    const int l15 = lane & 15, lhi = lane >> 4;

    f32x4 acc[2][2] = {};

    for (int ks = 0; ks < KSTEPS; ++ks) {
        uint4 av[VPTA];
        #pragma unroll
        for (int v = 0; v < VPTA; ++v) {
            const int g = tid + v * 256, row = g >> 3, c8 = g & 7;
            av[v] = *reinterpret_cast<const uint4*>(
                A + (size_t)min(m0 + row, M - 1) * CINs + ks * 64 + c8 * 8);
        }
        uint4 wv[VPTW];
        #pragma unroll
        for (int v = 0; v < VPTW; ++v) {
            const int g = tid + v * 256, d = g >> 3, c8 = g & 7;
            wv[v] = *reinterpret_cast<const uint4*>(
                Wt + (size_t)(kpl * BN + d) * CINs + ks * 64 + c8 * 8);
        }

        __syncthreads();
        #pragma unroll
        for (int v = 0; v < VPTA; ++v) {
            const int g = tid + v * 256, row = g >> 3, c8 = g & 7;
            *reinterpret_cast<uint4*>(&As[(row * 64 + c8 * 8) ^ ((row & 7) << 3)]) = av[v];
        }
        #pragma unroll
        for (int v = 0; v < VPTW; ++v) {
            const int g = tid + v * 256, d = g >> 3, c8 = g & 7;
            *reinterpret_cast<uint4*>(&Ws[(d * 64 + c8 * 8) ^ ((d & 7) << 3)]) = wv[v];
        }
        __syncthreads();

        #pragma unroll
        for (int kk2 = 0; kk2 < 2; ++kk2) {
            const int kb = kk2 * 32 + lhi * 8;
            bf16x8 a[2], b[2];
            #pragma unroll
            for (int m = 0; m < 2; ++m) {
                const int row = wr * 32 + m * 16 + l15;
                a[m] = *reinterpret_cast<const bf16x8*>(&As[(row * 64 + kb) ^ ((row & 7) << 3)]);
            }
            #pragma unroll
            for (int n = 0; n < 2; ++n) {
                const int col = wc * 32 + n * 16 + l15;
                b[n] = *reinterpret_cast<const bf16x8*>(&Ws[(col * 64 + kb) ^ ((col & 7) << 3)]);
            }
            #pragma unroll
            for (int m = 0; m < 2; ++m)
                #pragma unroll
                for (int n = 0; n < 2; ++n)
                    acc[m][n] = __builtin_amdgcn_mfma_f32_16x16x32_bf16(a[m], b[n], acc[m][n], 0, 0, 0);
        }
        __syncthreads();
    }

    // coalesced full-line writeback through LDS (reuse As)
    unsigned short* Cs = As;
    #pragma unroll
    for (int n = 0; n < 2; ++n) {
        const int col = wc * 32 + n * 16 + l15;
        #pragma unroll
        for (int m = 0; m < 2; ++m)
            #pragma unroll
            for (int i = 0; i < 4; ++i)
                Cs[(wr * 32 + m * 16 + lhi * 4 + i) * BN + col] = f2bf(acc[m][n][i]);
    }
    __syncthreads();
    constexpr int RPT = BN / 8;
    constexpr int CV  = BM * BN / 8 / 256;
    #pragma unroll
    for (int v = 0; v < CV; ++v) {
        const int g = tid + v * 256, row = g / RPT, c8 = g % RPT;
        const int grow = m0 + row;
        if (grow < M)
            *reinterpret_cast<uint4*>(&Z[((size_t)kpl * M + grow) * BN + c8 * 8]) =
                *reinterpret_cast<const uint4*>(&Cs[row * BN + c8 * 8]);
    }
}

// ---------------------------------------------------------------------------
// dual-source plane-major gather-reduce, t<->XCD pinned:
// out[t,n,:] = relu(b + sum_k Zu[k][t*Nu+up[nb_k]] + Zb[k][t*N+nb_k])
// ---------------------------------------------------------------------------
template<int COUT>
__global__ __launch_bounds__(256) void epi_dual_kernel(
    const unsigned short* __restrict__ Zu, const unsigned short* __restrict__ Zb,
    const int* __restrict__ up, const int* __restrict__ neigh,
    int N, int Nu, int Bt, const float* __restrict__ bias,
    unsigned short* __restrict__ out)
{
    constexpr int C8 = COUT / 8;
    const int xcd = blockIdx.x & 7;
    int idx = blockIdx.x >> 3;
    const int hi = (idx >= Bt) ? 1 : 0;
    const int t  = 2 * xcd + hi;
    const int e  = (idx - hi * Bt) * 256 + threadIdx.x;
    if (e >= N * C8) return;
    const int c8 = e % C8;
    const int n  = e / C8;
    const size_t Mu = (size_t)T * Nu, Mb = (size_t)T * N;
    const int* nb = neigh + n * K;

    float s[8];
    #pragma unroll
    for (int j = 0; j < 8; ++j) s[j] = bias[c8 * 8 + j];
    #pragma unroll
    for (int k = 0; k < K; ++k) {
        const int jn = nb[k];
        const int ju = up[jn];
        const uint4 vu = *reinterpret_cast<const uint4*>(
            &Zu[((size_t)k * Mu + (size_t)t * Nu + ju) * COUT + c8 * 8]);
        const uint4 vb = *reinterpret_cast<const uint4*>(
            &Zb[((size_t)k * Mb + (size_t)t * N + jn) * COUT + c8 * 8]);
        const unsigned short* pu = reinterpret_cast<const unsigned short*>(&vu);
        const unsigned short* pb = reinterpret_cast<const unsigned short*>(&vb);
        #pragma unroll
        for (int j = 0; j < 8; ++j) s[j] += bf2f(pu[j]) + bf2f(pb[j]);
    }
    unsigned short o[8];
    #pragma unroll
    for (int j = 0; j < 8; ++j) o[j] = f2bf(fmaxf(s[j], 0.f));
    *reinterpret_cast<uint4*>(&out[((size_t)t * N + n) * COUT + c8 * 8]) =
        *reinterpret_cast<const uint4*>(o);
}

// ---------------------------------------------------------------------------
// rd path (conv1/conv2): per-wave 32x32 MFMA tile (r6, unchanged)
// ---------------------------------------------------------------------------
template<int CIN, int COUT, class Loader>
__device__ __forceinline__ void sconv_tile(
    const Loader& ldr, const int* __restrict__ neigh, int N, int t,
    int tile_m, int tile_n,
    const unsigned short* __restrict__ Wt, const float* __restrict__ bias,
    unsigned short* __restrict__ out)
{
    constexpr int KC     = K * CIN;
    constexpr int CHUNKS = CIN / 32;
    constexpr int STEPS  = K * CHUNKS;
    constexpr int D      = STEPS < 3 ? STEPS : 3;

    const int lane = threadIdx.x & 63;
    const int l15 = lane & 15, lhi = lane >> 4;

    const int r0 = tile_m * 32 + l15;
    const int row0 = min(r0, N - 1), row1 = min(r0 + 16, N - 1);

    typename Loader::Ref ref0[K], ref1[K];
    #pragma unroll
    for (int k = 0; k < K; ++k) {
        ref0[k] = ldr.prep(t, neigh[row0 * K + k]);
        ref1[k] = ldr.prep(t, neigh[row1 * K + k]);
    }

    const int col0 = tile_n * 32 + l15;
    const unsigned short* w0p = Wt + (size_t)col0 * KC + lhi * 8;
    const unsigned short* w1p = w0p + (size_t)16 * KC;

    uint4 qa0[D], qa1[D], qb0[D], qb1[D];

    auto issue = [&](int s, int slot) {
        const int k = s / CHUNKS, c = s - k * CHUNKS;
        const int c8 = c * 4 + lhi;
        qa0[slot] = ldr.chunk(ref0[k], c8);
        qa1[slot] = ldr.chunk(ref1[k], c8);
        qb0[slot] = *reinterpret_cast<const uint4*>(w0p + k * CIN + c * 32);
        qb1[slot] = *reinterpret_cast<const uint4*>(w1p + k * CIN + c * 32);
    };

    f32x4 acc[2][2] = {};

    #pragma unroll
    for (int s = 0; s < D; ++s) issue(s, s);
    __builtin_amdgcn_sched_barrier(0);

    #pragma unroll
    for (int s = 0; s < STEPS; ++s) {
        const int slot = s % D;
        const bf16x8 a0 = __builtin_bit_cast(bf16x8, qa0[slot]);
        const bf16x8 a1 = __builtin_bit_cast(bf16x8, qa1[slot]);
        const bf16x8 b0 = __builtin_bit_cast(bf16x8, qb0[slot]);
        const bf16x8 b1 = __builtin_bit_cast(bf16x8, qb1[slot]);
        acc[0][0] = __builtin_amdgcn_mfma_f32_16x16x32_bf16(a0, b0, acc[0][0], 0, 0, 0);
        acc[0][1] = __builtin_amdgcn_mfma_f32_16x16x32_bf16(a0, b1, acc[0][1], 0, 0, 0);
        acc[1][0] = __builtin_amdgcn_mfma_f32_16x16x32_bf16(a1, b0, acc[1][0], 0, 0, 0);
        acc[1][1] = __builtin_amdgcn_mfma_f32_16x16x32_bf16(a1, b1, acc[1][1], 0, 0, 0);
        if (s + D < STEPS) issue(s + D, slot);
        __builtin_amdgcn_sched_barrier(0);
    }

    #pragma unroll
    for (int n = 0; n < 2; ++n) {
        const int gcol = tile_n * 32 + n * 16 + l15;
        const float bv = bias[gcol];
        #pragma unroll
        for (int m = 0; m < 2; ++m) {
            #pragma unroll
            for (int i = 0; i < 4; ++i) {
                const int grow = tile_m * 32 + m * 16 + lhi * 4 + i;
                if (grow < N)
                    out[((size_t)t * N + grow) * COUT + gcol] =
                        f2bf(fmaxf(acc[m][n][i] + bv, 0.f));
            }
        }
    }
}

template<int CIN, int COUT, class Loader>
__global__ __launch_bounds__(64, 2) void sconv_rd2_kernel(
    Loader lf, Loader la, const int* __restrict__ neigh, int N, int U,
    const unsigned short* __restrict__ Wtf, const unsigned short* __restrict__ Wta,
    const float* __restrict__ bf_, const float* __restrict__ ba_,
    unsigned short* __restrict__ of_, unsigned short* __restrict__ oa_)
{
    constexpr int TN = COUT / 32;
    const int xcd = blockIdx.x & 7;
    int idx = blockIdx.x >> 3;
    const int sel = idx & 1; idx >>= 1;
    const int hi = (idx >= U) ? 1 : 0;
    const int t  = 2 * xcd + hi;
    const int w  = idx - hi * U;
    const Loader L = sel ? la : lf;
    const unsigned short* Wt = sel ? Wta : Wtf;
    const float* bias = sel ? ba_ : bf_;
    unsigned short* out = sel ? oa_ : of_;
    sconv_tile<CIN, COUT, Loader>(L, neigh, N, t, w / TN, w % TN, Wt, bias, out);
}

// ---------------------------------------------------------------------------
// conv9: logits fp32 from bf16 cv8
// ---------------------------------------------------------------------------
__global__ __launch_bounds__(256) void conv9_kernel(
    const unsigned short* __restrict__ cv8, const int* __restrict__ neigh5,
    const float* __restrict__ W9, const float* __restrict__ b9,
    float* __restrict__ logits)
{
    const int idx = blockIdx.x * 256 + threadIdx.x;
    if (idx >= T * n5) return;
    const int n = idx % n5;
    const int t = idx / n5;
    float acc = b9[0];
    const int* nb = neigh5 + n * K;
    #pragma unroll
    for (int k = 0; k < K; ++k) {
        const uint4* row = reinterpret_cast<const uint4*>(cv8 + ((size_t)t * n5 + nb[k]) * 32);
        const float* wk = W9 + k * 32;
        #pragma unroll
        for (int c4 = 0; c4 < 4; ++c4) {
            const uint4 v = row[c4];
            const unsigned short* s = reinterpret_cast<const unsigned short*>(&v);
            #pragma unroll
            for (int jj = 0; jj < 8; ++jj)
                acc = fmaf(bf2f(s[jj]), wk[c4 * 8 + jj], acc);
        }
    }
    logits[idx] = acc;
}

// ---------------------------------------------------------------------------
// softmax
// ---------------------------------------------------------------------------
__global__ __launch_bounds__(1024) void softmax_kernel(
    const float* __restrict__ logits, float* __restrict__ out)
{
    const int t = blockIdx.x, tid = threadIdx.x;
    const float* x = logits + (size_t)t * n5;
    float* y = out + (size_t)t * n5;
    __shared__ float redmax[16], redsum[16];

    float mx = -FLT_MAX;
    for (int i = tid; i < n5; i += 1024) mx = fmaxf(mx, x[i]);
    #pragma unroll
    for (int m = 1; m < 64; m <<= 1) mx = fmaxf(mx, __shfl_xor(mx, m));
    if ((tid & 63) == 0) redmax[tid >> 6] = mx;
    __syncthreads();
    mx = redmax[0];
    #pragma unroll
    for (int i = 1; i < 16; ++i) mx = fmaxf(mx, redmax[i]);

    float s = 0.f;
    for (int i = tid; i < n5; i += 1024) s += expf(x[i] - mx);
    #pragma unroll
    for (int m = 1; m < 64; m <<= 1) s += __shfl_xor(s, m);
    if ((tid & 63) == 0) redsum[tid >> 6] = s;
    __syncthreads();
    s = 0.f;
    #pragma unroll
    for (int i = 0; i < 16; ++i) s += redsum[i];

    for (int i = tid; i < n5; i += 1024) y[i] = expf(x[i] - mx) / s;
}

// ---------------------------------------------------------------------------
extern "C" void kernel_launch(void* const* d_in, const int* in_sizes, int n_in,
                              void* d_out, int out_size, void* d_ws, size_t ws_size,
                              hipStream_t stream)
{
    const float* frame = (const float*)d_in[0];
    const float* aem   = (const float*)d_in[1];
    const float* W0f = (const float*)d_in[2];
    const float* b0f = (const float*)d_in[3];
    const float* W0a = (const float*)d_in[4];
    const float* b0a = (const float*)d_in[5];
    const float* W1f = (const float*)d_in[6];
    const float* b1f = (const float*)d_in[7];
    const float* W1a = (const float*)d_in[8];
    const float* b1a = (const float*)d_in[9];
    const float* W2f = (const float*)d_in[10];
    const float* b2f = (const float*)d_in[11];
    const float* W2a = (const float*)d_in[12];
    const float* b2a = (const float*)d_in[13];
    const float* W7  = (const float*)d_in[14];
    const float* b7  = (const float*)d_in[15];
    const float* W8  = (const float*)d_in[16];
    const float* b8  = (const float*)d_in[17];
    const float* W9  = (const float*)d_in[18];
    const float* b9  = (const float*)d_in[19];
    const int* neigh5 = (const int*)d_in[20];
    const int* neigh4 = (const int*)d_in[21];
    const int* neigh3 = (const int*)d_in[22];
    const int* pool5  = (const int*)d_in[23];
    const int* pool4  = (const int*)d_in[24];
    const int* up4    = (const int*)d_in[25];
    const int* up5    = (const int*)d_in[26];

    unsigned short* wsu = (unsigned short*)d_ws;
    size_t off = 0;
    auto ua = [&](size_t n) {
        unsigned short* p = wsu + off; off += (n + 7) & ~(size_t)7; return p;
    };
    unsigned short* c0f  = ua((size_t)T * n5 * 32);
    unsigned short* c0a  = ua((size_t)T * n5 * 32);
    unsigned short* att0 = ua((size_t)T * n5 * 64);
    unsigned short* p0f  = ua((size_t)T * n4 * 32);
    unsigned short* p0a  = ua((size_t)T * n4 * 32);
    unsigned short* c1f  = ua((size_t)T * n4 * 64);
    unsigned short* c1a  = ua((size_t)T * n4 * 64);
    unsigned short* att1 = ua((size_t)T * n4 * 128);
    unsigned short* p1f  = ua((size_t)T * n3 * 64);
    unsigned short* p1a  = ua((size_t)T * n3 * 64);
    unsigned short* c2f  = ua((size_t)T * n3 * 128);
    unsigned short* c2a  = ua((size_t)T * n3 * 128);
    unsigned short* att2 = ua((size_t)T * n3 * 256);
    unsigned short* cv7  = ua((size_t)T * n4 * 64);
    unsigned short* cv8  = ua((size_t)T * n5 * 32);
    unsigned short* Wt1f = ua((size_t)64 * 224);
    unsigned short* Wt1a = ua((size_t)64 * 224);
    unsigned short* Wt2f = ua((size_t)128 * 448);
    unsigned short* Wt2a = ua((size_t)128 * 448);
    unsigned short* Wt7a = ua((size_t)448 * 256);
    unsigned short* Wt7b = ua((size_t)448 * 128);
    unsigned short* Wt8a = ua((size_t)224 * 64);
    unsigned short* Wt8b = ua((size_t)224 * 64);
    // Z arena, plane-major. phase1: Z2[7][T*n3][64] + Zb7[7][T*n4][64]
    //                       phase2: Z7s[7][T*n4][32] + Zb8[7][T*n5][32]
    unsigned short* arena = ua((size_t)K * T * n4 * 32 + (size_t)K * T * n5 * 32);
    unsigned short* Z2  = arena;
    unsigned short* Zb7 = arena + (size_t)K * T * n3 * 64;
    unsigned short* Z7s = arena;
    unsigned short* Zb8 = arena + (size_t)K * T * n4 * 32;
    float* lgt = (float*)(wsu + ((off + 1) & ~(size_t)1));

    wprep_all_kernel<<<1344, 256, 0, stream>>>(
        W1f, W1a, W2f, W2a, W7, W8,
        Wt1f, Wt1a, Wt2f, Wt2a, Wt7a, Wt7b, Wt8a, Wt8b);

    conv0_kernel<<<T * ((n5 + 7) / 8), 256, 0, stream>>>(
        frame, aem, W0f, b0f, W0a, b0a, neigh5, c0f, c0a, att0);

    {
        const int thr = T * n4 * (32 / 8);
        pool_kernel<32><<<(thr + 255) / 256, 256, 0, stream>>>(c0f, pool5, n5, n4, p0f);
        pool_kernel<32><<<(thr + 255) / 256, 256, 0, stream>>>(c0a, pool5, n5, n4, p0a);
    }

    // conv1 f+a fused rd: U=162
    {
        constexpr int U = 81 * 2;
        sconv_rd2_kernel<32, 64><<<8 * 4 * U, 64, 0, stream>>>(
            PlainB16{(const uint4*)p0f, n4, 4}, PlainB16{(const uint4*)p0a, n4, 4},
            neigh4, n4, U, Wt1f, Wt1a, b1f, b1a, c1f, c1a);
    }
    cosatt_kernel<64, n4><<<(T * n4 + 3) / 4, 256, 0, stream>>>(c1f, c1a, att1);

    {
        const int thr = T * n3 * (64 / 8);
        pool_kernel<64><<<(thr + 255) / 256, 256, 0, stream>>>(c1f, pool4, n4, n3, p1f);
        pool_kernel<64><<<(thr + 255) / 256, 256, 0, stream>>>(c1a, pool4, n4, n3, p1a);
    }

    // conv2 f+a fused rd: U=84
    {
        constexpr int U = 21 * 4;
        sconv_rd2_kernel<64, 128><<<8 * 4 * U, 64, 0, stream>>>(
            PlainB16{(const uint4*)p1f, n3, 8}, PlainB16{(const uint4*)p1a, n3, 8},
            neigh3, n3, U, Wt2f, Wt2a, b2f, b2a, c2f, c2a);
    }
    cosatt_kernel<128, n3><<<(T * n3 + 3) / 4, 256, 0, stream>>>(c2f, c2a, att2);

    // conv7 = two plane-major streaming GEMMs + pinned dual gather-reduce
    {
        constexpr int M2 = T * n3;            // 10272
        constexpr int Mb = T * n4;            // 40992
        gemm_p_kernel<256, 64, 64><<<((M2 + 63) / 64) * K, 256, 0, stream>>>(
            att2, M2, Wt7a, Z2);
        gemm_p_kernel<128, 64, 64><<<((Mb + 63) / 64) * K, 256, 0, stream>>>(
            att1, Mb, Wt7b, Zb7);
        constexpr int Bt = (n4 * 8 + 255) / 256;   // 81
        epi_dual_kernel<64><<<8 * 2 * Bt, 256, 0, stream>>>(
            Z2, Zb7, up4, neigh4, n4, n3, Bt, b7, cv7);
    }

    // conv8 = two plane-major streaming GEMMs + pinned dual gather-reduce
    {
        constexpr int Ms = T * n4;            // 40992
        constexpr int Mb = T * n5;            // 163872
        gemm_p_kernel<64, 32, 128><<<((Ms + 127) / 128) * K, 256, 0, stream>>>(
            cv7, Ms, Wt8a, Z7s);
        gemm_p_kernel<64, 32, 128><<<((Mb + 127) / 128) * K, 256, 0, stream>>>(
            att0, Mb, Wt8b, Zb8);
        constexpr int Bt = (n5 * 4 + 255) / 256;   // 161
        epi_dual_kernel<32><<<8 * 2 * Bt, 256, 0, stream>>>(
            Z7s, Zb8, up5, neigh5, n5, n4, Bt, b8, cv8);
    }

    conv9_kernel<<<(T * n5 + 255) / 256, 256, 0, stream>>>(cv8, neigh5, W9, b9, lgt);

    softmax_kernel<<<T, 1024, 0, stream>>>(lgt, (float*)d_out);
}

// Round 10
// 265.363 us; speedup vs baseline: 1.3813x; 1.3051x over previous
//
#include <hip/hip_runtime.h>
#include <cfloat>
#include <cstdint>

// Model2c round 10: r7's pinned gather-fused GEMM (best verified: FETCH=15MB,
// gathers L2-resident) with the ONE thing it got wrong fixed: the Z write path.
//   r7: Z[m][k*COUT+d], 16 scalar ushort stores/lane -> WRITE 108MB vs 36.7 logical.
//   now: Z[k][t][N][COUT] plane-major; each block writes ONE contiguous 8KB
//        region via LDS-staged full-line uint4 stores.
// Epilogues read plane-major, t<->XCD pinned. conv1/conv2 keep r6 rd path.

constexpr int T  = 16;
constexpr int n5 = 10242, n4 = 2562, n3 = 642;
constexpr int K  = 7;

using bf16x8 = __attribute__((ext_vector_type(8))) short;
using f32x4  = __attribute__((ext_vector_type(4))) float;

static __device__ __forceinline__ float bf2f(unsigned short u) {
    return __uint_as_float((unsigned)u << 16);
}
static __device__ __forceinline__ unsigned short f2bf(float x) {
    unsigned u = __float_as_uint(x);
    u += 0x7FFF + ((u >> 16) & 1);
    return (unsigned short)(u >> 16);
}

// ---------------------------------------------------------------------------
// conv0: c0f/c0a (bf16) + fused cos -> att0 = bf16[c0f*m | c0a*m]
// ---------------------------------------------------------------------------
__global__ __launch_bounds__(256) void conv0_kernel(
    const float* __restrict__ frame, const float* __restrict__ aem,
    const float* __restrict__ W0f, const float* __restrict__ b0f,
    const float* __restrict__ W0a, const float* __restrict__ b0a,
    const int* __restrict__ neigh5,
    unsigned short* __restrict__ c0f, unsigned short* __restrict__ c0a,
    unsigned short* __restrict__ att0)
{
    const int g = threadIdx.x >> 5;
    const int d = threadIdx.x & 31;
    const int per_t = (n5 + 7) / 8;
    const int t = blockIdx.x / per_t;
    const int n = (blockIdx.x % per_t) * 8 + g;
    if (n >= n5) return;

    float accf = b0f[d];
    float acca = b0a[d];
    const int* nb = neigh5 + n * K;
    #pragma unroll
    for (int k = 0; k < K; ++k) {
        const int j = nb[k];
        const float* fr = frame + ((size_t)t * n5 + j) * 3;
        const float av = aem[(size_t)t * n5 + j];
        accf = fmaf(fr[0], W0f[(k * 3 + 0) * 32 + d], accf);
        accf = fmaf(fr[1], W0f[(k * 3 + 1) * 32 + d], accf);
        accf = fmaf(fr[2], W0f[(k * 3 + 2) * 32 + d], accf);
        acca = fmaf(av, W0a[k * 32 + d], acca);
    }
    accf = fmaxf(accf, 0.f);
    acca = fmaxf(acca, 0.f);

    float dot = accf * acca, ff = accf * accf, aa = acca * acca;
    #pragma unroll
    for (int m = 1; m < 32; m <<= 1) {
        dot += __shfl_xor(dot, m, 32);
        ff  += __shfl_xor(ff,  m, 32);
        aa  += __shfl_xor(aa,  m, 32);
    }
    const float mm = dot / fmaxf(sqrtf(ff) * sqrtf(aa), 1e-8f);
    const size_t base = ((size_t)t * n5 + n) * 32;
    c0f[base + d] = f2bf(accf);
    c0a[base + d] = f2bf(acca);
    const size_t abase = ((size_t)t * n5 + n) * 64;
    att0[abase + d]      = f2bf(accf * mm);
    att0[abase + 32 + d] = f2bf(acca * mm);
}

// ---------------------------------------------------------------------------
// pool (bf16 -> bf16)
// ---------------------------------------------------------------------------
template<int C>
__global__ __launch_bounds__(256) void pool_kernel(
    const unsigned short* __restrict__ in, const int* __restrict__ pidx,
    int Nin, int Nout, unsigned short* __restrict__ out)
{
    constexpr int C8 = C / 8;
    const int idx = blockIdx.x * 256 + threadIdx.x;
    if (idx >= T * Nout * C8) return;
    const int c8 = idx % C8;
    const int n  = (idx / C8) % Nout;
    const int t  = idx / (C8 * Nout);
    const int* pp = pidx + n * K;
    float m[8];
    #pragma unroll
    for (int j = 0; j < 8; ++j) m[j] = -FLT_MAX;
    #pragma unroll
    for (int k = 0; k < K; ++k) {
        const uint4 v = reinterpret_cast<const uint4*>(in)[((size_t)t * Nin + pp[k]) * C8 + c8];
        const unsigned short* s = reinterpret_cast<const unsigned short*>(&v);
        #pragma unroll
        for (int j = 0; j < 8; ++j) m[j] = fmaxf(m[j], bf2f(s[j]));
    }
    unsigned short o[8];
    #pragma unroll
    for (int j = 0; j < 8; ++j) o[j] = f2bf(m[j]);
    reinterpret_cast<uint4*>(out)[((size_t)t * Nout + n) * C8 + c8] =
        *reinterpret_cast<const uint4*>(o);
}

// ---------------------------------------------------------------------------
// cosatt: m = cos(f,a); att = bf16[f*m | a*m]
// ---------------------------------------------------------------------------
template<int C, int NN>
__global__ __launch_bounds__(256) void cosatt_kernel(
    const unsigned short* __restrict__ f, const unsigned short* __restrict__ a,
    unsigned short* __restrict__ att)
{
    constexpr int CPL = C / 64;
    const int w = threadIdx.x >> 6, lane = threadIdx.x & 63;
    const int idx = blockIdx.x * 4 + w;
    if (idx >= T * NN) return;
    const unsigned short* fr = f + (size_t)idx * C;
    const unsigned short* ar = a + (size_t)idx * C;
    float xs[CPL], ys[CPL];
    float dot = 0.f, ff = 0.f, aa = 0.f;
    #pragma unroll
    for (int i = 0; i < CPL; ++i) {
        const float x = bf2f(fr[lane + i * 64]);
        const float y = bf2f(ar[lane + i * 64]);
        xs[i] = x; ys[i] = y;
        dot = fmaf(x, y, dot);
        ff  = fmaf(x, x, ff);
        aa  = fmaf(y, y, aa);
    }
    #pragma unroll
    for (int msk = 1; msk < 64; msk <<= 1) {
        dot += __shfl_xor(dot, msk);
        ff  += __shfl_xor(ff,  msk);
        aa  += __shfl_xor(aa,  msk);
    }
    const float m = dot / fmaxf(sqrtf(ff) * sqrtf(aa), 1e-8f);
    unsigned short* orow = att + (size_t)idx * 2 * C;
    #pragma unroll
    for (int i = 0; i < CPL; ++i) {
        orow[lane + i * 64]     = f2bf(xs[i] * m);
        orow[C + lane + i * 64] = f2bf(ys[i] * m);
    }
}

// ---------------------------------------------------------------------------
// Loaders
// ---------------------------------------------------------------------------
struct PlainB16 {                    // rd path (conv1/conv2)
    const uint4* x; int N; int C8;
    struct Ref { int o; };
    __device__ __forceinline__ Ref prep(int t, int node) const {
        return { (int)(((size_t)t * N + node) * C8) };
    }
    __device__ __forceinline__ uint4 chunk(const Ref& r, int c8) const {
        return x[r.o + c8];
    }
};

struct Cat7B16 {   // GEMM A: [att2[up4[m]] (256ch,32 chunks) | att1[m] (128ch,16)]
    const uint4* att2; const uint4* att1; const int* up4;
    __device__ __forceinline__ uint4 row8(int t, int node, int c8) const {
        if (c8 < 32)
            return att2[((size_t)t * n3 + up4[node]) * 32 + c8];
        return att1[((size_t)t * n4 + node) * 16 + (c8 - 32)];
    }
};

struct Cat8B16 {   // GEMM A: [cv7[up5[m]] (64ch,8 chunks) | att0[m] (64ch,8)]
    const uint4* cv7; const uint4* att0; const int* up5;
    __device__ __forceinline__ uint4 row8(int t, int node, int c8) const {
        if (c8 < 8)
            return cv7[((size_t)t * n4 + up5[node]) * 8 + c8];
        return att0[((size_t)t * n5 + node) * 8 + (c8 - 8)];
    }
};

// ---------------------------------------------------------------------------
// weight prep: Wt[d][kc] bf16 <- W[kc][d] fp32  (r3 layout, used by all paths)
// ---------------------------------------------------------------------------
__global__ __launch_bounds__(256) void wprep_all_kernel(
    const float* __restrict__ W1f, const float* __restrict__ W1a,
    const float* __restrict__ W2f, const float* __restrict__ W2a,
    const float* __restrict__ W7,  const float* __restrict__ W8,
    unsigned short* __restrict__ Wt1f, unsigned short* __restrict__ Wt1a,
    unsigned short* __restrict__ Wt2f, unsigned short* __restrict__ Wt2a,
    unsigned short* __restrict__ Wt7,  unsigned short* __restrict__ Wt8)
{
    int idx = blockIdx.x * 256 + threadIdx.x;
    const float* W; unsigned short* Wt; int KCv, CO;
    if (idx < 14336)       { W = W1f; Wt = Wt1f; KCv = 224;  CO = 64;  }
    else if (idx < 28672)  { idx -= 14336;  W = W1a; Wt = Wt1a; KCv = 224;  CO = 64;  }
    else if (idx < 86016)  { idx -= 28672;  W = W2f; Wt = Wt2f; KCv = 448;  CO = 128; }
    else if (idx < 143360) { idx -= 86016;  W = W2a; Wt = Wt2a; KCv = 448;  CO = 128; }
    else if (idx < 315392) { idx -= 143360; W = W7;  Wt = Wt7;  KCv = 2688; CO = 64;  }
    else                   { idx -= 315392; W = W8;  Wt = Wt8;  KCv = 896;  CO = 32;  }
    const int d = idx / KCv, kc = idx - d * KCv;
    Wt[idx] = f2bf(W[(size_t)kc * CO + d]);
}

// ---------------------------------------------------------------------------
// Gather-fused GEMM, plane-major output (r7 + fixed write path):
//   Z[kk][t][m][d] = sum_c A(t,m,c) * W[kk][c][d]
// Block = (t, tile_m, kk). A gathered via Loader (L2-resident under pinning,
// r7-verified FETCH=15MB). C written back via LDS as full-line uint4 into a
// contiguous BM*COUT*2B region owned exclusively by this block.
// ---------------------------------------------------------------------------
template<int CIN, int COUT, int BM, class Loader>
__global__ __launch_bounds__(256) void gemm_zp_kernel(
    Loader ldr, int N, int Mt,
    const unsigned short* __restrict__ Wt,    // [COUT][K*CIN]
    unsigned short* __restrict__ Z)           // [K][T][N][COUT]
{
    constexpr int KC    = K * CIN;
    constexpr int BK    = 64;
    constexpr int KSTEPS = CIN / BK;
    constexpr int U4R   = BK / 8;             // 8
    constexpr int WGR_N = COUT / 32;          // 1 or 2
    constexpr int WGR_M = 4 / WGR_N;
    constexpr int VPTA  = BM * U4R / 256;
    constexpr int VPTW  = COUT * U4R / 256;
    static_assert(BM == WGR_M * 32 && CIN % BK == 0 && VPTW >= 1 && BM * COUT <= BM * BK);

    __shared__ __align__(16) unsigned short As[BM * BK];
    __shared__ __align__(16) unsigned short Ws[COUT * BK];

    const int xcd = blockIdx.x & 7;
    int rest = blockIdx.x >> 3;               // [0, 2*Mt*K)
    const int half = Mt * K;
    const int hi = (rest >= half) ? 1 : 0;
    const int t  = 2 * xcd + hi;
    const int j  = rest - hi * half;
    const int tile_m = j / K;
    const int kk_    = j % K;

    const int tid = threadIdx.x, lane = tid & 63, wave = tid >> 6;
    const int wr = wave / WGR_N, wc = wave % WGR_N;
    const int l15 = lane & 15, lhi = lane >> 4;
    const int m0 = tile_m * BM;

    f32x4 acc[2][2] = {};

    for (int ks = 0; ks < KSTEPS; ++ks) {
        uint4 av[VPTA];
        #pragma unroll
        for (int v = 0; v < VPTA; ++v) {
            const int g = tid + v * 256, row = g / U4R, c8 = g % U4R;
            av[v] = ldr.row8(t, min(m0 + row, N - 1), ks * U4R + c8);
        }
        uint4 wv[VPTW];
        #pragma unroll
        for (int v = 0; v < VPTW; ++v) {
            const int g = tid + v * 256, d = g / U4R, c8 = g % U4R;
            wv[v] = *reinterpret_cast<const uint4*>(
                Wt + (size_t)d * KC + kk_ * CIN + ks * BK + c8 * 8);
        }

        __syncthreads();   // prior iteration's ds_reads done
        #pragma unroll
        for (int v = 0; v < VPTA; ++v) {
            const int g = tid + v * 256, row = g / U4R, c8 = g % U4R;
            *reinterpret_cast<uint4*>(&As[(row * BK + c8 * 8) ^ ((row & 7) << 3)]) = av[v];
        }
        #pragma unroll
        for (int v = 0; v < VPTW; ++v) {
            const int g = tid + v * 256, d = g / U4R, c8 = g % U4R;
            *reinterpret_cast<uint4*>(&Ws[(d * BK + c8 * 8) ^ ((d & 7) << 3)]) = wv[v];
        }
        __syncthreads();

        #pragma unroll
        for (int kk2 = 0; kk2 < 2; ++kk2) {
            const int kb = kk2 * 32 + lhi * 8;
            bf16x8 a[2], b[2];
            #pragma unroll
            for (int m = 0; m < 2; ++m) {
                const int row = wr * 32 + m * 16 + l15;
                a[m] = *reinterpret_cast<const bf16x8*>(&As[(row * BK + kb) ^ ((row & 7) << 3)]);
            }
            #pragma unroll
            for (int n = 0; n < 2; ++n) {
                const int col = wc * 32 + n * 16 + l15;
                b[n] = *reinterpret_cast<const bf16x8*>(&Ws[(col * BK + kb) ^ ((col & 7) << 3)]);
            }
            #pragma unroll
            for (int m = 0; m < 2; ++m)
                #pragma unroll
                for (int n = 0; n < 2; ++n)
                    acc[m][n] = __builtin_amdgcn_mfma_f32_16x16x32_bf16(a[m], b[n], acc[m][n], 0, 0, 0);
        }
    }

    // LDS-staged full-line writeback into contiguous plane-major region
    __syncthreads();
    unsigned short* Cs = As;                  // BM*COUT shorts fits in As
    #pragma unroll
    for (int n = 0; n < 2; ++n) {
        const int col = wc * 32 + n * 16 + l15;
        #pragma unroll
        for (int m = 0; m < 2; ++m)
            #pragma unroll
            for (int i = 0; i < 4; ++i)
                Cs[(wr * 32 + m * 16 + lhi * 4 + i) * COUT + col] = f2bf(acc[m][n][i]);
    }
    __syncthreads();
    constexpr int RPT = COUT / 8;
    constexpr int CV  = BM * COUT / 8 / 256;
    #pragma unroll
    for (int v = 0; v < CV; ++v) {
        const int g = tid + v * 256, row = g / RPT, c8 = g % RPT;
        const int grow = m0 + row;
        if (grow < N)
            *reinterpret_cast<uint4*>(
                &Z[(((size_t)kk_ * T + t) * N + grow) * COUT + c8 * 8]) =
                *reinterpret_cast<const uint4*>(&Cs[row * COUT + c8 * 8]);
    }
}

// ---------------------------------------------------------------------------
// plane-major gather-reduce epilogue, t<->XCD pinned:
// out[t,n,:] = relu(b + sum_k Z[k][t][neigh[n,k]][:])
// ---------------------------------------------------------------------------
template<int COUT>
__global__ __launch_bounds__(256) void epi_p_kernel(
    const unsigned short* __restrict__ Z, const int* __restrict__ neigh,
    int N, int Bt, const float* __restrict__ bias, unsigned short* __restrict__ out)
{
    constexpr int C8 = COUT / 8;
    const int xcd = blockIdx.x & 7;
    int idx = blockIdx.x >> 3;
    const int hi = (idx >= Bt) ? 1 : 0;
    const int t  = 2 * xcd + hi;
    const int e  = (idx - hi * Bt) * 256 + threadIdx.x;
    if (e >= N * C8) return;
    const int c8 = e % C8;
    const int n  = e / C8;
    const int* nb = neigh + n * K;

    float s[8];
    #pragma unroll
    for (int j = 0; j < 8; ++j) s[j] = bias[c8 * 8 + j];
    #pragma unroll
    for (int k = 0; k < K; ++k) {
        const uint4 v = *reinterpret_cast<const uint4*>(
            &Z[(((size_t)k * T + t) * N + nb[k]) * COUT + c8 * 8]);
        const unsigned short* p = reinterpret_cast<const unsigned short*>(&v);
        #pragma unroll
        for (int j = 0; j < 8; ++j) s[j] += bf2f(p[j]);
    }
    unsigned short o[8];
    #pragma unroll
    for (int j = 0; j < 8; ++j) o[j] = f2bf(fmaxf(s[j], 0.f));
    *reinterpret_cast<uint4*>(&out[((size_t)t * N + n) * COUT + c8 * 8]) =
        *reinterpret_cast<const uint4*>(o);
}

// ---------------------------------------------------------------------------
// rd path (conv1/conv2): per-wave 32x32 MFMA tile (r6, unchanged)
// ---------------------------------------------------------------------------
template<int CIN, int COUT, class Loader>
__device__ __forceinline__ void sconv_tile(
    const Loader& ldr, const int* __restrict__ neigh, int N, int t,
    int tile_m, int tile_n,
    const unsigned short* __restrict__ Wt, const float* __restrict__ bias,
    unsigned short* __restrict__ out)
{
    constexpr int KC     = K * CIN;
    constexpr int CHUNKS = CIN / 32;
    constexpr int STEPS  = K * CHUNKS;
    constexpr int D      = STEPS < 3 ? STEPS : 3;

    const int lane = threadIdx.x & 63;
    const int l15 = lane & 15, lhi = lane >> 4;

    const int r0 = tile_m * 32 + l15;
    const int row0 = min(r0, N - 1), row1 = min(r0 + 16, N - 1);

    typename Loader::Ref ref0[K], ref1[K];
    #pragma unroll
    for (int k = 0; k < K; ++k) {
        ref0[k] = ldr.prep(t, neigh[row0 * K + k]);
        ref1[k] = ldr.prep(t, neigh[row1 * K + k]);
    }

    const int col0 = tile_n * 32 + l15;
    const unsigned short* w0p = Wt + (size_t)col0 * KC + lhi * 8;
    const unsigned short* w1p = w0p + (size_t)16 * KC;

    uint4 qa0[D], qa1[D], qb0[D], qb1[D];

    auto issue = [&](int s, int slot) {
        const int k = s / CHUNKS, c = s - k * CHUNKS;
        const int c8 = c * 4 + lhi;
        qa0[slot] = ldr.chunk(ref0[k], c8);
        qa1[slot] = ldr.chunk(ref1[k], c8);
        qb0[slot] = *reinterpret_cast<const uint4*>(w0p + k * CIN + c * 32);
        qb1[slot] = *reinterpret_cast<const uint4*>(w1p + k * CIN + c * 32);
    };

    f32x4 acc[2][2] = {};

    #pragma unroll
    for (int s = 0; s < D; ++s) issue(s, s);
    __builtin_amdgcn_sched_barrier(0);

    #pragma unroll
    for (int s = 0; s < STEPS; ++s) {
        const int slot = s % D;
        const bf16x8 a0 = __builtin_bit_cast(bf16x8, qa0[slot]);
        const bf16x8 a1 = __builtin_bit_cast(bf16x8, qa1[slot]);
        const bf16x8 b0 = __builtin_bit_cast(bf16x8, qb0[slot]);
        const bf16x8 b1 = __builtin_bit_cast(bf16x8, qb1[slot]);
        acc[0][0] = __builtin_amdgcn_mfma_f32_16x16x32_bf16(a0, b0, acc[0][0], 0, 0, 0);
        acc[0][1] = __builtin_amdgcn_mfma_f32_16x16x32_bf16(a0, b1, acc[0][1], 0, 0, 0);
        acc[1][0] = __builtin_amdgcn_mfma_f32_16x16x32_bf16(a1, b0, acc[1][0], 0, 0, 0);
        acc[1][1] = __builtin_amdgcn_mfma_f32_16x16x32_bf16(a1, b1, acc[1][1], 0, 0, 0);
        if (s + D < STEPS) issue(s + D, slot);
        __builtin_amdgcn_sched_barrier(0);
    }

    #pragma unroll
    for (int n = 0; n < 2; ++n) {
        const int gcol = tile_n * 32 + n * 16 + l15;
        const float bv = bias[gcol];
        #pragma unroll
        for (int m = 0; m < 2; ++m) {
            #pragma unroll
            for (int i = 0; i < 4; ++i) {
                const int grow = tile_m * 32 + m * 16 + lhi * 4 + i;
                if (grow < N)
                    out[((size_t)t * N + grow) * COUT + gcol] =
                        f2bf(fmaxf(acc[m][n][i] + bv, 0.f));
            }
        }
    }
}

template<int CIN, int COUT, class Loader>
__global__ __launch_bounds__(64, 2) void sconv_rd2_kernel(
    Loader lf, Loader la, const int* __restrict__ neigh, int N, int U,
    const unsigned short* __restrict__ Wtf, const unsigned short* __restrict__ Wta,
    const float* __restrict__ bf_, const float* __restrict__ ba_,
    unsigned short* __restrict__ of_, unsigned short* __restrict__ oa_)
{
    constexpr int TN = COUT / 32;
    const int xcd = blockIdx.x & 7;
    int idx = blockIdx.x >> 3;
    const int sel = idx & 1; idx >>= 1;
    const int hi = (idx >= U) ? 1 : 0;
    const int t  = 2 * xcd + hi;
    const int w  = idx - hi * U;
    const Loader L = sel ? la : lf;
    const unsigned short* Wt = sel ? Wta : Wtf;
    const float* bias = sel ? ba_ : bf_;
    unsigned short* out = sel ? oa_ : of_;
    sconv_tile<CIN, COUT, Loader>(L, neigh, N, t, w / TN, w % TN, Wt, bias, out);
}

// ---------------------------------------------------------------------------
// conv9: logits fp32 from bf16 cv8
// ---------------------------------------------------------------------------
__global__ __launch_bounds__(256) void conv9_kernel(
    const unsigned short* __restrict__ cv8, const int* __restrict__ neigh5,
    const float* __restrict__ W9, const float* __restrict__ b9,
    float* __restrict__ logits)
{
    const int idx = blockIdx.x * 256 + threadIdx.x;
    if (idx >= T * n5) return;
    const int n = idx % n5;
    const int t = idx / n5;
    float acc = b9[0];
    const int* nb = neigh5 + n * K;
    #pragma unroll
    for (int k = 0; k < K; ++k) {
        const uint4* row = reinterpret_cast<const uint4*>(cv8 + ((size_t)t * n5 + nb[k]) * 32);
        const float* wk = W9 + k * 32;
        #pragma unroll
        for (int c4 = 0; c4 < 4; ++c4) {
            const uint4 v = row[c4];
            const unsigned short* s = reinterpret_cast<const unsigned short*>(&v);
            #pragma unroll
            for (int jj = 0; jj < 8; ++jj)
                acc = fmaf(bf2f(s[jj]), wk[c4 * 8 + jj], acc);
        }
    }
    logits[idx] = acc;
}

// ---------------------------------------------------------------------------
// softmax
// ---------------------------------------------------------------------------
__global__ __launch_bounds__(1024) void softmax_kernel(
    const float* __restrict__ logits, float* __restrict__ out)
{
    const int t = blockIdx.x, tid = threadIdx.x;
    const float* x = logits + (size_t)t * n5;
    float* y = out + (size_t)t * n5;
    __shared__ float redmax[16], redsum[16];

    float mx = -FLT_MAX;
    for (int i = tid; i < n5; i += 1024) mx = fmaxf(mx, x[i]);
    #pragma unroll
    for (int m = 1; m < 64; m <<= 1) mx = fmaxf(mx, __shfl_xor(mx, m));
    if ((tid & 63) == 0) redmax[tid >> 6] = mx;
    __syncthreads();
    mx = redmax[0];
    #pragma unroll
    for (int i = 1; i < 16; ++i) mx = fmaxf(mx, redmax[i]);

    float s = 0.f;
    for (int i = tid; i < n5; i += 1024) s += expf(x[i] - mx);
    #pragma unroll
    for (int m = 1; m < 64; m <<= 1) s += __shfl_xor(s, m);
    if ((tid & 63) == 0) redsum[tid >> 6] = s;
    __syncthreads();
    s = 0.f;
    #pragma unroll
    for (int i = 0; i < 16; ++i) s += redsum[i];

    for (int i = tid; i < n5; i += 1024) y[i] = expf(x[i] - mx) / s;
}

// ---------------------------------------------------------------------------
extern "C" void kernel_launch(void* const* d_in, const int* in_sizes, int n_in,
                              void* d_out, int out_size, void* d_ws, size_t ws_size,
                              hipStream_t stream)
{
    const float* frame = (const float*)d_in[0];
    const float* aem   = (const float*)d_in[1];
    const float* W0f = (const float*)d_in[2];
    const float* b0f = (const float*)d_in[3];
    const float* W0a = (const float*)d_in[4];
    const float* b0a = (const float*)d_in[5];
    const float* W1f = (const float*)d_in[6];
    const float* b1f = (const float*)d_in[7];
    const float* W1a = (const float*)d_in[8];
    const float* b1a = (const float*)d_in[9];
    const float* W2f = (const float*)d_in[10];
    const float* b2f = (const float*)d_in[11];
    const float* W2a = (const float*)d_in[12];
    const float* b2a = (const float*)d_in[13];
    const float* W7  = (const float*)d_in[14];
    const float* b7  = (const float*)d_in[15];
    const float* W8  = (const float*)d_in[16];
    const float* b8  = (const float*)d_in[17];
    const float* W9  = (const float*)d_in[18];
    const float* b9  = (const float*)d_in[19];
    const int* neigh5 = (const int*)d_in[20];
    const int* neigh4 = (const int*)d_in[21];
    const int* neigh3 = (const int*)d_in[22];
    const int* pool5  = (const int*)d_in[23];
    const int* pool4  = (const int*)d_in[24];
    const int* up4    = (const int*)d_in[25];
    const int* up5    = (const int*)d_in[26];

    unsigned short* wsu = (unsigned short*)d_ws;
    size_t off = 0;
    auto ua = [&](size_t n) {   // 128B-aligned slabs
        unsigned short* p = wsu + off; off += (n + 63) & ~(size_t)63; return p;
    };
    unsigned short* c0f  = ua((size_t)T * n5 * 32);
    unsigned short* c0a  = ua((size_t)T * n5 * 32);
    unsigned short* att0 = ua((size_t)T * n5 * 64);
    unsigned short* p0f  = ua((size_t)T * n4 * 32);
    unsigned short* p0a  = ua((size_t)T * n4 * 32);
    unsigned short* c1f  = ua((size_t)T * n4 * 64);
    unsigned short* c1a  = ua((size_t)T * n4 * 64);
    unsigned short* att1 = ua((size_t)T * n4 * 128);
    unsigned short* p1f  = ua((size_t)T * n3 * 64);
    unsigned short* p1a  = ua((size_t)T * n3 * 64);
    unsigned short* c2f  = ua((size_t)T * n3 * 128);
    unsigned short* c2a  = ua((size_t)T * n3 * 128);
    unsigned short* att2 = ua((size_t)T * n3 * 256);
    unsigned short* cv7  = ua((size_t)T * n4 * 64);
    unsigned short* cv8  = ua((size_t)T * n5 * 32);
    unsigned short* Wt1f = ua((size_t)64 * 224);
    unsigned short* Wt1a = ua((size_t)64 * 224);
    unsigned short* Wt2f = ua((size_t)128 * 448);
    unsigned short* Wt2a = ua((size_t)128 * 448);
    unsigned short* Wt7  = ua((size_t)64 * 2688);
    unsigned short* Wt8  = ua((size_t)32 * 896);
    // Z arena: phase1 Z7[7][T][n4][64] (18.4M), phase2 Z8[7][T][n5][32] (36.7M)
    unsigned short* Zbuf = ua((size_t)K * T * n5 * 32);
    float* lgt = (float*)(wsu + ((off + 1) & ~(size_t)1));

    wprep_all_kernel<<<1344, 256, 0, stream>>>(
        W1f, W1a, W2f, W2a, W7, W8, Wt1f, Wt1a, Wt2f, Wt2a, Wt7, Wt8);

    conv0_kernel<<<T * ((n5 + 7) / 8), 256, 0, stream>>>(
        frame, aem, W0f, b0f, W0a, b0a, neigh5, c0f, c0a, att0);

    {
        const int thr = T * n4 * (32 / 8);
        pool_kernel<32><<<(thr + 255) / 256, 256, 0, stream>>>(c0f, pool5, n5, n4, p0f);
        pool_kernel<32><<<(thr + 255) / 256, 256, 0, stream>>>(c0a, pool5, n5, n4, p0a);
    }

    // conv1 f+a fused rd: U=162
    {
        constexpr int U = 81 * 2;
        sconv_rd2_kernel<32, 64><<<8 * 4 * U, 64, 0, stream>>>(
            PlainB16{(const uint4*)p0f, n4, 4}, PlainB16{(const uint4*)p0a, n4, 4},
            neigh4, n4, U, Wt1f, Wt1a, b1f, b1a, c1f, c1a);
    }
    cosatt_kernel<64, n4><<<(T * n4 + 3) / 4, 256, 0, stream>>>(c1f, c1a, att1);

    {
        const int thr = T * n3 * (64 / 8);
        pool_kernel<64><<<(thr + 255) / 256, 256, 0, stream>>>(c1f, pool4, n4, n3, p1f);
        pool_kernel<64><<<(thr + 255) / 256, 256, 0, stream>>>(c1a, pool4, n4, n3, p1a);
    }

    // conv2 f+a fused rd: U=84
    {
        constexpr int U = 21 * 4;
        sconv_rd2_kernel<64, 128><<<8 * 4 * U, 64, 0, stream>>>(
            PlainB16{(const uint4*)p1f, n3, 8}, PlainB16{(const uint4*)p1a, n3, 8},
            neigh3, n3, U, Wt2f, Wt2a, b2f, b2a, c2f, c2a);
    }
    cosatt_kernel<128, n3><<<(T * n3 + 3) / 4, 256, 0, stream>>>(c2f, c2a, att2);

    // conv7 = pinned gather-fused GEMM (plane-major Z) + pinned gather-reduce
    {
        constexpr int Mt = (n4 + 63) / 64;     // 41
        gemm_zp_kernel<384, 64, 64><<<16 * Mt * K, 256, 0, stream>>>(
            Cat7B16{(const uint4*)att2, (const uint4*)att1, up4}, n4, Mt, Wt7, Zbuf);
        constexpr int Bt = (n4 * 8 + 255) / 256;   // 81
        epi_p_kernel<64><<<8 * 2 * Bt, 256, 0, stream>>>(
            Zbuf, neigh4, n4, Bt, b7, cv7);
    }

    // conv8 = pinned gather-fused GEMM (plane-major Z) + pinned gather-reduce
    {
        constexpr int Mt = (n5 + 127) / 128;   // 81
        gemm_zp_kernel<128, 32, 128><<<16 * Mt * K, 256, 0, stream>>>(
            Cat8B16{(const uint4*)cv7, (const uint4*)att0, up5}, n5, Mt, Wt8, Zbuf);
        constexpr int Bt = (n5 * 4 + 255) / 256;   // 161
        epi_p_kernel<32><<<8 * 2 * Bt, 256, 0, stream>>>(
            Zbuf, neigh5, n5, Bt, b8, cv8);
    }

    conv9_kernel<<<(T * n5 + 255) / 256, 256, 0, stream>>>(cv8, neigh5, W9, b9, lgt);

    softmax_kernel<<<T, 1024, 0, stream>>>(lgt, (float*)d_out);
}